// Round 8
// baseline (1175.954 us; speedup 1.0000x reference)
//
#include <hip/hip_runtime.h>

#define DIM 64
#define LN_EPS 1e-5f
#define XS_STRIDE 68
#define MAXNB 1024   // supports n <= 65536 (n = 50000 here)
#define EPB 4096     // edges per binA block

// ---------------- bucketed edge binning (once per call) ----------------
// bucket b = dst >> 6  (64 nodes per bucket, aligned with k_layer tiles)

// per-block LDS histogram of dst buckets -> atomic merge to global
__global__ __launch_bounds__(256) void k_countb(const int* __restrict__ dst,
                                                int* __restrict__ bcnt, int E, int nb) {
    __shared__ int h[MAXNB];
    int t = threadIdx.x;
    for (int i = t; i < nb; i += 256) h[i] = 0;
    __syncthreads();
    int e0 = blockIdx.x * EPB;
#pragma unroll 4
    for (int j = 0; j < EPB / 256; j++) {
        int e = e0 + j * 256 + t;
        if (e < E) atomicAdd(&h[dst[e] >> 6], 1);
    }
    __syncthreads();
    for (int i = t; i < nb; i += 256) if (h[i]) atomicAdd(&bcnt[i], h[i]);
}

// exclusive scan of bcnt[0..nb) -> bstart[0..nb]  (single block)
__global__ __launch_bounds__(256) void k_scanb(const int* __restrict__ bcnt,
                                               int* __restrict__ bstart, int nb) {
    __shared__ int wsum[4];
    int t = threadIdx.x;
    int c0 = t * 4;
    int x0 = (c0 + 0 < nb) ? bcnt[c0 + 0] : 0;
    int x1 = (c0 + 1 < nb) ? bcnt[c0 + 1] : 0;
    int x2 = (c0 + 2 < nb) ? bcnt[c0 + 2] : 0;
    int x3 = (c0 + 3 < nb) ? bcnt[c0 + 3] : 0;
    int s = x0 + x1 + x2 + x3;
    int lane = t & 63, wave = t >> 6;
    int incl = s;
#pragma unroll
    for (int d = 1; d < 64; d <<= 1) { int u = __shfl_up(incl, d, 64); if (lane >= d) incl += u; }
    if (lane == 63) wsum[wave] = incl;
    __syncthreads();
    int wo = 0;
    for (int w = 0; w < wave; w++) wo += wsum[w];
    int excl = wo + incl - s;
    if (c0 + 0 < nb) bstart[c0 + 0] = excl;
    if (c0 + 1 < nb) bstart[c0 + 1] = excl + x0;
    if (c0 + 2 < nb) bstart[c0 + 2] = excl + x0 + x1;
    if (c0 + 3 < nb) bstart[c0 + 3] = excl + x0 + x1 + x2;
    if (t == 255) bstart[nb] = wo + incl;   // total = E
}

// Pass A: LDS-sort a 4096-edge chunk by bucket, reserve global segments,
// write packed entries (src<<6 | dst&63) coalesced & time-local.
__global__ __launch_bounds__(256) void k_binA(const int* __restrict__ src,
                                              const int* __restrict__ dst,
                                              const int* __restrict__ bstart,
                                              int* __restrict__ bfill,
                                              int* __restrict__ ebuf, int E, int nb) {
    __shared__ int lhist[MAXNB];
    __shared__ int lbase[MAXNB];
    __shared__ int gbase[MAXNB];
    __shared__ int staged[EPB];
    __shared__ int gpos[EPB];
    __shared__ int wsum[4];
    int t = threadIdx.x;
    for (int i = t; i < nb; i += 256) lhist[i] = 0;
    __syncthreads();

    int e0 = blockIdx.x * EPB;
    int ecnt = min(EPB, E - e0);
    int ss[EPB / 256], dd[EPB / 256];
    int ne = 0;
#pragma unroll
    for (int j = 0; j < EPB / 256; j++) {
        int e = e0 + j * 256 + t;
        if (e < E) { ss[ne] = src[e]; dd[ne] = dst[e]; ne++; }
    }
    for (int j = 0; j < ne; j++) atomicAdd(&lhist[dd[j] >> 6], 1);
    __syncthreads();

    {   // exclusive scan lhist -> lbase (lhist preserved)
        int c0 = t * 4;
        int x0 = (c0 + 0 < nb) ? lhist[c0 + 0] : 0;
        int x1 = (c0 + 1 < nb) ? lhist[c0 + 1] : 0;
        int x2 = (c0 + 2 < nb) ? lhist[c0 + 2] : 0;
        int x3 = (c0 + 3 < nb) ? lhist[c0 + 3] : 0;
        int s = x0 + x1 + x2 + x3;
        int lane = t & 63, wave = t >> 6;
        int incl = s;
#pragma unroll
        for (int d = 1; d < 64; d <<= 1) { int u = __shfl_up(incl, d, 64); if (lane >= d) incl += u; }
        if (lane == 63) wsum[wave] = incl;
        __syncthreads();
        int wo = 0;
        for (int w = 0; w < wave; w++) wo += wsum[w];
        int excl = wo + incl - s;
        if (c0 + 0 < nb) lbase[c0 + 0] = excl;
        if (c0 + 1 < nb) lbase[c0 + 1] = excl + x0;
        if (c0 + 2 < nb) lbase[c0 + 2] = excl + x0 + x1;
        if (c0 + 3 < nb) lbase[c0 + 3] = excl + x0 + x1 + x2;
    }
    __syncthreads();

    for (int i = t; i < nb; i += 256) {
        int c = lhist[i];
        gbase[i] = c ? (bstart[i] + atomicAdd(&bfill[i], c)) : 0;
        lhist[i] = 0;
    }
    __syncthreads();

    for (int j = 0; j < ne; j++) {
        int b = dd[j] >> 6;
        int ofs = atomicAdd(&lhist[b], 1);
        int p = lbase[b] + ofs;
        staged[p] = (ss[j] << 6) | (dd[j] & 63);
        gpos[p] = gbase[b] + ofs;
    }
    __syncthreads();

    for (int i = t; i < ecnt; i += 256) ebuf[gpos[i]] = staged[i];
}

// Pass B (lite): per-bucket degree histogram -> dinv only.
__global__ __launch_bounds__(256) void k_binB(const int* __restrict__ bstart,
                                              const int* __restrict__ ebuf,
                                              float* __restrict__ dinv, int n) {
    __shared__ int ldeg[64];
    int b = blockIdx.x;
    int t = threadIdx.x;
    int e0 = bstart[b], e1 = bstart[b + 1];
    if (t < 64) ldeg[t] = 0;
    __syncthreads();
    for (int i = e0 + t; i < e1; i += 256) atomicAdd(&ldeg[ebuf[i] & 63], 1);
    __syncthreads();
    if (t < 64) {
        int node = b * 64 + t;
        if (node < n) dinv[node] = rsqrtf((float)(ldeg[t] + 1));
    }
}

// xs[i,:] = dinv[i] * x[i,:]   (float4 over n*16)
__global__ void k_prescale(const float* __restrict__ x, const float* __restrict__ dinv,
                           float* __restrict__ xs, int n16) {
    int i = blockIdx.x * blockDim.x + threadIdx.x;
    if (i >= n16) return;
    float di = dinv[i >> 4];
    float4 v = ((const float4*)x)[i];
    v.x *= di; v.y *= di; v.z *= di; v.w *= di;
    ((float4*)xs)[i] = v;
}

// ---------------- fused per-layer kernel (256 threads = 4 waves) ----------------
// Phase 1 (edge-parallel): self-init the 64-row LDS tile with xin, then the 4
//   waves split this tile's bucket segment into batches of 8 edges; per edge:
//   wave-uniform entry load, lane=feature gather, LDS atomicAdd into the dst
//   row. 8 independent gathers in flight per wave, no per-row serial chain.
// Phase 2 (R5-proven): register-tile GEMM (4 rows x 4 cols/lane); the dinv[row]
//   aggregate scale is applied to acc[j] post-GEMM (linearity), then
//   bias + LayerNorm + ReLU (+ dinv pre-scale for the next layer's input).
__global__ __launch_bounds__(256) void k_layer(const int* __restrict__ bstart,
                                               const int* __restrict__ ebuf,
                                               const float* __restrict__ dinv,
                                               const float* __restrict__ xin,
                                               const float* __restrict__ W,
                                               const float* __restrict__ b,
                                               const float* __restrict__ gamma,
                                               const float* __restrict__ beta,
                                               float* __restrict__ out, int n,
                                               int scale_out) {
    __shared__ float ws[DIM * DIM];
    __shared__ float xs[64 * XS_STRIDE];
    int t = threadIdx.x;
    int tile = blockIdx.x;
    int base = tile * 64;
    int wave = t >> 6, lane = t & 63;

    {   // stage W
        const float4* W4 = (const float4*)W;
        float4* ws4 = (float4*)ws;
#pragma unroll
        for (int i = 0; i < 4; i++) ws4[t + 256 * i] = W4[t + 256 * i];
    }

    // self-init the tile (unscaled aggregate accumulator)
#pragma unroll
    for (int rr = 0; rr < 16; rr++) {
        int lrow = wave * 16 + rr;
        int row = base + lrow;
        xs[lrow * XS_STRIDE + lane] = (row < n) ? xin[(size_t)row * DIM + lane] : 0.f;
    }
    __syncthreads();

    // edge-parallel aggregation over this tile's bucket segment
    int e0 = bstart[tile], e1 = bstart[tile + 1];
    int nbatch = (e1 - e0 + 7) >> 3;
    for (int k = wave; k < nbatch; k += 4) {
        int es = e0 + k * 8;
        int ee = min(es + 8, e1);
        if (ee - es == 8) {
            int v0 = ebuf[es + 0], v1 = ebuf[es + 1], v2 = ebuf[es + 2], v3 = ebuf[es + 3];
            int v4 = ebuf[es + 4], v5 = ebuf[es + 5], v6 = ebuf[es + 6], v7 = ebuf[es + 7];
            float f0 = xin[(size_t)(v0 >> 6) * DIM + lane];
            float f1 = xin[(size_t)(v1 >> 6) * DIM + lane];
            float f2 = xin[(size_t)(v2 >> 6) * DIM + lane];
            float f3 = xin[(size_t)(v3 >> 6) * DIM + lane];
            float f4 = xin[(size_t)(v4 >> 6) * DIM + lane];
            float f5 = xin[(size_t)(v5 >> 6) * DIM + lane];
            float f6 = xin[(size_t)(v6 >> 6) * DIM + lane];
            float f7 = xin[(size_t)(v7 >> 6) * DIM + lane];
            atomicAdd(&xs[(v0 & 63) * XS_STRIDE + lane], f0);
            atomicAdd(&xs[(v1 & 63) * XS_STRIDE + lane], f1);
            atomicAdd(&xs[(v2 & 63) * XS_STRIDE + lane], f2);
            atomicAdd(&xs[(v3 & 63) * XS_STRIDE + lane], f3);
            atomicAdd(&xs[(v4 & 63) * XS_STRIDE + lane], f4);
            atomicAdd(&xs[(v5 & 63) * XS_STRIDE + lane], f5);
            atomicAdd(&xs[(v6 & 63) * XS_STRIDE + lane], f6);
            atomicAdd(&xs[(v7 & 63) * XS_STRIDE + lane], f7);
        } else {
            for (int e = es; e < ee; e++) {
                int v = ebuf[e];
                atomicAdd(&xs[(v & 63) * XS_STRIDE + lane],
                          xin[(size_t)(v >> 6) * DIM + lane]);
            }
        }
    }
    __syncthreads();

    // ---- phase 2: register-tile GEMM + epilogue (R5 structure) ----
    int rgrp = lane >> 4;
    int c4 = lane & 15;
    int row0 = wave * 16 + rgrp * 4;

    float4 acc[4];
#pragma unroll
    for (int j = 0; j < 4; j++) acc[j] = make_float4(0.f, 0.f, 0.f, 0.f);

    for (int kc = 0; kc < 16; kc++) {
        float4 w0 = *(const float4*)(ws + (4 * kc + 0) * DIM + c4 * 4);
        float4 w1 = *(const float4*)(ws + (4 * kc + 1) * DIM + c4 * 4);
        float4 w2 = *(const float4*)(ws + (4 * kc + 2) * DIM + c4 * 4);
        float4 w3 = *(const float4*)(ws + (4 * kc + 3) * DIM + c4 * 4);
#pragma unroll
        for (int j = 0; j < 4; j++) {
            float4 xv = *(const float4*)(xs + (row0 + j) * XS_STRIDE + kc * 4);
            acc[j].x = fmaf(xv.x, w0.x, acc[j].x);
            acc[j].y = fmaf(xv.x, w0.y, acc[j].y);
            acc[j].z = fmaf(xv.x, w0.z, acc[j].z);
            acc[j].w = fmaf(xv.x, w0.w, acc[j].w);
            acc[j].x = fmaf(xv.y, w1.x, acc[j].x);
            acc[j].y = fmaf(xv.y, w1.y, acc[j].y);
            acc[j].z = fmaf(xv.y, w1.z, acc[j].z);
            acc[j].w = fmaf(xv.y, w1.w, acc[j].w);
            acc[j].x = fmaf(xv.z, w2.x, acc[j].x);
            acc[j].y = fmaf(xv.z, w2.y, acc[j].y);
            acc[j].z = fmaf(xv.z, w2.z, acc[j].z);
            acc[j].w = fmaf(xv.z, w2.w, acc[j].w);
            acc[j].x = fmaf(xv.w, w3.x, acc[j].x);
            acc[j].y = fmaf(xv.w, w3.y, acc[j].y);
            acc[j].z = fmaf(xv.w, w3.z, acc[j].z);
            acc[j].w = fmaf(xv.w, w3.w, acc[j].w);
        }
    }

    float4 b4  = *(const float4*)(b + c4 * 4);
    float4 g4  = *(const float4*)(gamma + c4 * 4);
    float4 be4 = *(const float4*)(beta + c4 * 4);
#pragma unroll
    for (int j = 0; j < 4; j++) {
        int grow = base + row0 + j;
        if (grow >= n) continue;
        float dvr = dinv[grow];           // aggregate scale, applied post-GEMM
        float4 v = make_float4(fmaf(acc[j].x, dvr, b4.x), fmaf(acc[j].y, dvr, b4.y),
                               fmaf(acc[j].z, dvr, b4.z), fmaf(acc[j].w, dvr, b4.w));
        float s = v.x + v.y + v.z + v.w;
        s += __shfl_xor(s, 1, 64);
        s += __shfl_xor(s, 2, 64);
        s += __shfl_xor(s, 4, 64);
        s += __shfl_xor(s, 8, 64);
        float mu = s * (1.0f / 64.0f);
        float4 d = make_float4(v.x - mu, v.y - mu, v.z - mu, v.w - mu);
        float q = d.x * d.x + d.y * d.y + d.z * d.z + d.w * d.w;
        q += __shfl_xor(q, 1, 64);
        q += __shfl_xor(q, 2, 64);
        q += __shfl_xor(q, 4, 64);
        q += __shfl_xor(q, 8, 64);
        float rstd = rsqrtf(q * (1.0f / 64.0f) + LN_EPS);
        float4 y = make_float4(fmaxf(fmaf(d.x * rstd, g4.x, be4.x), 0.f),
                               fmaxf(fmaf(d.y * rstd, g4.y, be4.y), 0.f),
                               fmaxf(fmaf(d.z * rstd, g4.z, be4.z), 0.f),
                               fmaxf(fmaf(d.w * rstd, g4.w, be4.w), 0.f));
        if (scale_out) {
            y.x *= dvr; y.y *= dvr; y.z *= dvr; y.w *= dvr;
        }
        *(float4*)(out + (size_t)grow * DIM + c4 * 4) = y;
    }
}

// ---------------- launch ----------------

extern "C" void kernel_launch(void* const* d_in, const int* in_sizes, int n_in,
                              void* d_out, int out_size, void* d_ws, size_t ws_size,
                              hipStream_t stream) {
    const float* x      = (const float*)d_in[0];
    const int*   ei     = (const int*)  d_in[1];
    const float* Ws     = (const float*)d_in[2];
    const float* bs     = (const float*)d_in[3];
    const float* gammas = (const float*)d_in[4];
    const float* betas  = (const float*)d_in[5];
    float* out = (float*)d_out;

    int n = in_sizes[0] / DIM;
    int E = in_sizes[1] / 2;
    int n_layers = in_sizes[2] / (DIM * DIM);
    int nb = (n + 63) / 64;

    const int* srcp = ei;
    const int* dstp = ei + E;

    // ws: bcnt[nb+1] | bfill[nb+1] | bstart[nb+1] | dinv[n] | ebuf[E] | (align16) xsA[n*64]
    int* bcnt     = (int*)d_ws;
    int* bfill    = bcnt + (nb + 1);
    int* bstart   = bfill + (nb + 1);
    float* dinv   = (float*)(bstart + (nb + 1));
    int* ebuf     = (int*)(dinv + n);
    uintptr_t xraw = (uintptr_t)(ebuf + E);
    xraw = (xraw + 15u) & ~(uintptr_t)15u;
    float* xsA    = (float*)xraw;

    int nb_ea = (E + EPB - 1) / EPB;

    hipMemsetAsync(bcnt, 0, sizeof(int) * 2 * (nb + 1), stream);  // bcnt + bfill
    k_countb<<<nb_ea, 256, 0, stream>>>(dstp, bcnt, E, nb);
    k_scanb <<<1, 256, 0, stream>>>(bcnt, bstart, nb);
    k_binA  <<<nb_ea, 256, 0, stream>>>(srcp, dstp, bstart, bfill, ebuf, E, nb);
    k_binB  <<<nb, 256, 0, stream>>>(bstart, ebuf, dinv, n);

    // ping-pong xsA <-> d_out so layer (n_layers-1) lands in d_out
    float* buf0 = ((n_layers & 1) == 0) ? out : xsA;
    k_prescale<<<(n * 16 + 255) / 256, 256, 0, stream>>>(x, dinv, buf0, n * 16);

    float* cur = buf0;
    for (int i = 0; i < n_layers; i++) {
        float* dst = (cur == xsA) ? out : xsA;
        if (i == n_layers - 1) dst = out;
        int scale = (i == n_layers - 1) ? 0 : 1;
        k_layer<<<nb, 256, 0, stream>>>(bstart, ebuf, dinv, cur,
                                        Ws + (size_t)i * DIM * DIM,
                                        bs + (size_t)i * DIM,
                                        gammas + (size_t)i * DIM,
                                        betas + (size_t)i * DIM,
                                        dst, n, scale);
        cur = dst;
    }
}